// Round 5
// baseline (236.124 us; speedup 1.0000x reference)
//
#include <hip/hip_runtime.h>

// ---------------- types / helpers ----------------
typedef unsigned short u16;
typedef float f32x4 __attribute__((ext_vector_type(4)));
typedef short bf16x8 __attribute__((ext_vector_type(8)));

__device__ __forceinline__ u16 f2bf(float f) {
    unsigned u = __float_as_uint(f);
    u = (u + 0x7FFFu + ((u >> 16) & 1u)) >> 16;
    return (u16)u;
}

#define LOG2E 1.4426950408889634f

#if __has_builtin(__builtin_amdgcn_exp2f)
__device__ __forceinline__ float exp2_fast(float x) { return __builtin_amdgcn_exp2f(x); }
#else
__device__ __forceinline__ float exp2_fast(float x) { return __expf(x * 0.6931471805599453f); }
#endif

__device__ __forceinline__ unsigned pack2bf(float a, float b) {
    unsigned ua = __float_as_uint(a) + 0x8000u;
    unsigned ub = __float_as_uint(b) + 0x8000u;
#if __has_builtin(__builtin_amdgcn_perm)
    return __builtin_amdgcn_perm(ub, ua, 0x07060302u);
#else
    return ((ua >> 16) & 0xFFFFu) | (ub & 0xFFFF0000u);
#endif
}

#if __has_builtin(__builtin_amdgcn_cvt_pk_bf16_f32)
typedef __bf16 bf2_t __attribute__((ext_vector_type(2)));
__device__ __forceinline__ unsigned cvtpk(float a, float b) {
    bf2_t r = __builtin_amdgcn_cvt_pk_bf16_f32(a, b);
    return __builtin_bit_cast(unsigned, r);
}
#else
__device__ __forceinline__ unsigned cvtpk(float a, float b) { return pack2bf(a, b); }
#endif

__device__ __forceinline__ bf16x8 bc8(uint4 u) { return __builtin_bit_cast(bf16x8, u); }

// async 16B/lane global->LDS DMA; lds dst = wave-uniform base + lane*16.
#if __has_builtin(__builtin_amdgcn_global_load_lds)
typedef const __attribute__((address_space(1))) void* as1cv;
typedef __attribute__((address_space(3))) void* as3v;
__device__ __forceinline__ void dma16(const void* g, void* lds_base, int lane) {
    __builtin_amdgcn_global_load_lds((as1cv)g, (as3v)lds_base, 16, 0, 0);
}
#else
__device__ __forceinline__ void dma16(const void* g, void* lds_base, int lane) {
    *(uint4*)((char*)lds_base + lane * 16) = *(const uint4*)g;
}
#endif

// Problem constants. DEDUP: reflect-pad duplicates keys; only 3136 unique source
// pixels. Multiplicity c in {1,2,4} folded into DATA (V pre-scaled, counts row).
#define BB 2
#define HH 56
#define SQ 3136
#define SKP 3200
#define VT_STRIDE 3200
#define CROWN 3584

// workspace offsets (u16 units); total 6,655,488 u16 = 13.3 MB
#define WS_Q    0         // 6272*256
#define WS_K    1605632   // 6272*256
#define WS_VT   3211264   // 512*3200
#define WS_WT   4849664   // 3*65536 fragment-packed weights
#define WS_CB   5046272   // 3584 u16: bf16 counts row
#define WS_XB   5049856   // 6272*256 bf16 x

// ---------------- kernel A: x -> bf16 pack (one pass) ----------------
__global__ __launch_bounds__(256) void xprep_kernel(const float* __restrict__ x,
                                                    u16* __restrict__ xb) {
    int gid = blockIdx.x * 256 + threadIdx.x;
    const float* src = x + (size_t)gid * 8;
    float4 f0 = *(const float4*)src;
    float4 f1 = *(const float4*)(src + 4);
    uint4 pk = (uint4){pack2bf(f0.x, f0.y), pack2bf(f0.z, f0.w),
                       pack2bf(f1.x, f1.y), pack2bf(f1.z, f1.w)};
    *(uint4*)&xb[(size_t)gid * 8] = pk;
}

// ---------------- kernel 0: weight fragment-pack + crow + VT pad zero -------------
__global__ __launch_bounds__(256) void wprep_kernel(const float* __restrict__ Wq,
                                                    const float* __restrict__ Wk,
                                                    const float* __restrict__ Wv,
                                                    u16* __restrict__ wtf,
                                                    u16* __restrict__ vtb,
                                                    u16* __restrict__ crow) {
    __shared__ u16 T[64][68];
    int mode = blockIdx.z;
    const float* W = (mode == 0) ? Wq : ((mode == 1) ? Wk : Wv);
    float sc = (mode == 0) ? LOG2E : 1.0f;
    int kx = blockIdx.x * 64, dx = blockIdx.y * 64;
    int tid = threadIdx.x;
    int r16 = tid >> 4, c4 = (tid & 15) * 4;
#pragma unroll
    for (int p = 0; p < 4; ++p) {
        int kr = p * 16 + r16;
        float4 f = *(const float4*)&W[(size_t)(kx + kr) * 256 + dx + c4];
        T[kr][c4 + 0] = f2bf(f.x * sc);
        T[kr][c4 + 1] = f2bf(f.y * sc);
        T[kr][c4 + 2] = f2bf(f.z * sc);
        T[kr][c4 + 3] = f2bf(f.w * sc);
    }
    __syncthreads();
    int l16 = tid & 15, nt_loc = (tid >> 4) & 3, quad = (tid >> 6) & 3;
#pragma unroll
    for (int s_loc = 0; s_loc < 2; ++s_loc) {
        int k0 = s_loc * 32 + quad * 8;
        int d_loc = nt_loc * 16 + l16;
        u16 tmp[8];
#pragma unroll
        for (int j = 0; j < 8; ++j) tmp[j] = T[k0 + j][d_loc];
        int d = dx + d_loc;
        int nz = d >> 7, ntg = (d >> 4) & 7;
        int s = (kx >> 5) + s_loc;
        int f = (nz * 8 + s) * 8 + ntg;
        int L = quad * 16 + l16;
        *(uint4*)&wtf[(size_t)mode * 65536 + (size_t)f * 512 + (size_t)L * 8] = *(uint4*)tmp;
    }
    if (mode == 1 && kx == 0 && dx == 0) {
        for (int i = tid; i < CROWN; i += 256) {
            u16 v = 0;
            if (i < SQ) {
                int rr = i / 56, cc = i - rr * 56;
                int mr = (((rr >= 1) && (rr <= 3)) || ((rr >= 52) && (rr <= 54))) ? 2 : 1;
                int mc = (((cc >= 1) && (cc <= 3)) || ((cc >= 52) && (cc <= 54))) ? 2 : 1;
                int prod = mr * mc;
                v = (prod == 1) ? (u16)0x3F80 : ((prod == 2) ? (u16)0x4000 : (u16)0x4080);
            }
            crow[i] = v;
        }
    }
    if (mode == 2 && kx == 0 && dx == 0) {
        for (int i = tid; i < 512 * 8; i += 256) {
            int row = i >> 3, c16 = i & 7;
            *(uint4*)&vtb[(size_t)row * VT_STRIDE + SQ + c16 * 8] = (uint4){0, 0, 0, 0};
        }
    }
}

// ---------------- kernel 1: projections (64x64 tile, B in LDS, A upfront) ----------
// grid (98, 3 modes, 4 nz2) = 1176 blocks; 32KB LDS -> 5 blocks/CU, single gen.
// Loop body is pure ds_read+MFMA: B staged once via global_load_lds, all 8 A-frags
// issued before the sync. x comes pre-packed bf16 (xprep).
__global__ __launch_bounds__(256, 5) void proj_kernel(const u16* __restrict__ xb,
                                                      const u16* __restrict__ wtf,
                                                      const float* __restrict__ bq,
                                                      const float* __restrict__ bk,
                                                      const float* __restrict__ bv,
                                                      u16* __restrict__ qout,
                                                      u16* __restrict__ kout,
                                                      u16* __restrict__ vtout) {
    __shared__ __align__(16) u16 Bl[16384];   // 32 frags x 512 u16
    int mode = blockIdx.y, nz2 = blockIdx.z;
    int mbase = blockIdx.x * 64;
    int tid = threadIdx.x;
    int wave = tid >> 6, lane = tid & 63, quad = (tid >> 4) & 3, l16 = tid & 15;
    int nz = nz2 >> 1, hi = nz2 & 1;
    const float* bias = (mode == 0) ? bq : ((mode == 1) ? bk : bv);
    float wsc = (mode == 0) ? LOG2E : 1.0f;
    const u16* wbase = wtf + (size_t)mode * 65536 + (size_t)nz * 32768 + hi * 2048;

    // stage 32 B-frags (8 per wave)
#pragma unroll
    for (int j = 0; j < 8; ++j) {
        int fi = wave * 8 + j;
        int s = fi >> 2, nt = fi & 3;
        dma16(wbase + s * 4096 + nt * 512 + lane * 8, (char*)Bl + fi * 1024, lane);
    }
    // all 8 A-frags issued before sync (drained by the barrier)
    int m_a = mbase + wave * 16 + l16;
    const u16* xr = xb + ((size_t)m_a << 8);
    bf16x8 aa[8];
#pragma unroll
    for (int s = 0; s < 8; ++s)
        aa[s] = *(const bf16x8*)&xr[s * 32 + quad * 8];
    __syncthreads();

    f32x4 acc[4];
#pragma unroll
    for (int i = 0; i < 4; i++) acc[i] = (f32x4){0.f, 0.f, 0.f, 0.f};

    if (mode == 2) {
#pragma unroll
        for (int s = 0; s < 8; ++s)
#pragma unroll
            for (int nt = 0; nt < 4; ++nt) {
                bf16x8 bf = *(const bf16x8*)&Bl[(s * 4 + nt) * 512 + lane * 8];
                acc[nt] = __builtin_amdgcn_mfma_f32_16x16x32_bf16(aa[s], bf, acc[nt], 0, 0, 0);
            }
    } else {
#pragma unroll
        for (int s = 0; s < 8; ++s)
#pragma unroll
            for (int nt = 0; nt < 4; ++nt) {
                bf16x8 bf = *(const bf16x8*)&Bl[(s * 4 + nt) * 512 + lane * 8];
                acc[nt] = __builtin_amdgcn_mfma_f32_16x16x32_bf16(bf, aa[s], acc[nt], 0, 0, 0);
            }
    }

    if (mode == 2) {
        int mrow_base = mbase + wave * 16 + quad * 4;
        float mult[4];
#pragma unroll
        for (int p = 0; p < 4; ++p) {
            int m = mrow_base + p;
            int kp = (m >= SQ) ? m - SQ : m;
            int rr = kp / 56, cc = kp - rr * 56;
            float mr = (((rr >= 1) && (rr <= 3)) || ((rr >= 52) && (rr <= 54))) ? 2.f : 1.f;
            float mc = (((cc >= 1) && (cc <= 3)) || ((cc >= 52) && (cc <= 54))) ? 2.f : 1.f;
            mult[p] = mr * mc;
        }
#pragma unroll
        for (int nt = 0; nt < 4; nt++) {
            int c = nz2 * 64 + nt * 16 + l16;
            float bvv = bias[c];
#pragma unroll
            for (int p = 0; p < 4; p += 2) {
                int m = mrow_base + p;
                int bb = (m >= SQ) ? 1 : 0;
                int kp = m - bb * SQ;
                unsigned pk = pack2bf((acc[nt][p] + bvv) * mult[p],
                                      (acc[nt][p + 1] + bvv) * mult[p + 1]);
                *(unsigned*)&vtout[(size_t)(bb * 256 + c) * VT_STRIDE + kp] = pk;
            }
        }
    } else {
        u16* outp = (mode == 0) ? qout : kout;
#pragma unroll
        for (int nt = 0; nt < 4; nt++) {
            int c0 = nz2 * 64 + nt * 16 + quad * 4;
            float4 b4 = *(const float4*)&bias[c0];
            float v0 = acc[nt][0] + b4.x * wsc;
            float v1 = acc[nt][1] + b4.y * wsc;
            float v2 = acc[nt][2] + b4.z * wsc;
            float v3 = acc[nt][3] + b4.w * wsc;
            uint2 pk = (uint2){pack2bf(v0, v1), pack2bf(v2, v3)};
            *(uint2*)&outp[((size_t)m_a << 8) + c0] = pk;
        }
    }
}

// ---------------- kernel 2: flash attention (8 waves, halved per-wave state) -------
// grid (16 bh, 49 qsub), 512 thr = 8 waves = 2 q-halves x 4 key-roles.
// Wave w: qh=w>>2 (queries qh*32..+32), role g=w&3 -> key tiles {g, g+4}.
// Each wave stages 1 K-tile + 1 V-group (tile w) per round; cross-wave reads
// synced by raw s_barrier + per-wave vmcnt(0) (prefetch r+1 stays in flight).
// LDS 39KB -> 4 blocks/CU x 8 waves: ~24.5 waves/CU resident (vs 12 before).
__global__ __launch_bounds__(512, 8) void attn_kernel(const u16* __restrict__ qb,
                                                      const u16* __restrict__ kb,
                                                      const u16* __restrict__ vtb,
                                                      const u16* __restrict__ crow,
                                                      const float* __restrict__ x,
                                                      const float* __restrict__ gammap,
                                                      float* __restrict__ out) {
    __shared__ __align__(16) u16 S[19968];   // 2 bufs x 8192 (K 4096 + V 4096), cnt @16384

    int tid = threadIdx.x;
    int w = tid >> 6, lane = tid & 63, quad = lane >> 4, l16 = lane & 15;
    int g = w & 3, qh = w >> 2;
    int bh = blockIdx.x;
    int b = bh >> 3, h = bh & 7;
    int qbase = b * SQ + blockIdx.y * 64 + qh * 32;

    bf16x8 qf[2];
#pragma unroll
    for (int i = 0; i < 2; ++i)
        qf[i] = *(const bf16x8*)&qb[((size_t)(qbase + i * 16 + l16) << 8) + h * 32 + quad * 8];

    const u16* kg = kb + ((size_t)(b * SQ) << 8) + h * 32;
    const u16* vg = vtb + (size_t)(b * 256 + h * 32) * VT_STRIDE;

    f32x4 o[2][2], lv[2];
#pragma unroll
    for (int i = 0; i < 2; ++i) {
        o[i][0] = (f32x4){0.f, 0.f, 0.f, 0.f};
        o[i][1] = (f32x4){0.f, 0.f, 0.f, 0.f};
        lv[i]   = (f32x4){0.f, 0.f, 0.f, 0.f};
    }

    // wave w stages K tile w and V group w (2 DMAs/round)
    auto stage = [&](int r_ch, int buf) {
        u16* base = &S[buf * 8192];
        int kbase = r_ch * 128;
        int grow = kbase + w * 16 + l16;
        if (grow > SQ - 1) grow = SQ - 1;
        dma16(kg + ((size_t)grow << 8) + (lane >> 4) * 8, base + w * 512, lane);
        int col = kbase + (2 * w + (lane >> 5)) * 8;
        dma16(vg + (size_t)(lane & 31) * VT_STRIDE + col, base + 4096 + w * 512, lane);
    };

    int tA = g, tB = g + 4;
    int vOffA = tA * 512 + (((quad >> 1) * 32 + l16) << 3) + (quad & 1) * 4;
    int vOffB = tB * 512 + (((quad >> 1) * 32 + l16) << 3) + (quad & 1) * 4;

    auto round_body = [&](int r, int bR) {
        const u16* Kl = &S[bR * 8192];
        const u16* Vl = Kl + 4096;
        const u16* cnt = &S[16384] + r * 128;
        bf16x8 kfA = *(const bf16x8*)&Kl[tA * 512 + lane * 8];
        bf16x8 kfB = *(const bf16x8*)&Kl[tB * 512 + lane * 8];
        uint2 ca = *(const uint2*)&cnt[tA * 16 + quad * 4];
        uint2 cc = *(const uint2*)&cnt[tB * 16 + quad * 4];
        bf16x8 cf = bc8((uint4){ca.x, ca.y, cc.x, cc.y});
        uint2 wA0 = *(const uint2*)&Vl[vOffA];
        uint2 wB0 = *(const uint2*)&Vl[vOffB];
        uint2 wA1 = *(const uint2*)&Vl[vOffA + 128];
        uint2 wB1 = *(const uint2*)&Vl[vOffB + 128];
        bf16x8 V0 = bc8((uint4){wA0.x, wA0.y, wB0.x, wB0.y});
        bf16x8 V1 = bc8((uint4){wA1.x, wA1.y, wB1.x, wB1.y});

        f32x4 z = (f32x4){0.f, 0.f, 0.f, 0.f};
        f32x4 eA[2], eB[2];
#pragma unroll
        for (int i = 0; i < 2; ++i)
            eA[i] = __builtin_amdgcn_mfma_f32_16x16x32_bf16(kfA, qf[i], z, 0, 0, 0);
#pragma unroll
        for (int i = 0; i < 2; ++i)
            eB[i] = __builtin_amdgcn_mfma_f32_16x16x32_bf16(kfB, qf[i], z, 0, 0, 0);

#pragma unroll
        for (int i = 0; i < 2; ++i) {
            float pA0 = exp2_fast(eA[i][0]), pA1 = exp2_fast(eA[i][1]);
            float pA2 = exp2_fast(eA[i][2]), pA3 = exp2_fast(eA[i][3]);
            float pB0 = exp2_fast(eB[i][0]), pB1 = exp2_fast(eB[i][1]);
            float pB2 = exp2_fast(eB[i][2]), pB3 = exp2_fast(eB[i][3]);
            bf16x8 pa = bc8((uint4){cvtpk(pA0, pA1), cvtpk(pA2, pA3),
                                    cvtpk(pB0, pB1), cvtpk(pB2, pB3)});
            o[i][0] = __builtin_amdgcn_mfma_f32_16x16x32_bf16(pa, V0, o[i][0], 0, 0, 0);
            o[i][1] = __builtin_amdgcn_mfma_f32_16x16x32_bf16(pa, V1, o[i][1], 0, 0, 0);
            lv[i]   = __builtin_amdgcn_mfma_f32_16x16x32_bf16(pa, cf, lv[i], 0, 0, 0);
        }
    };

    // prologue: counts (7 x 1KB across waves 0-6) + round 0
    if (w < 7) dma16(crow + w * 512 + lane * 8, (char*)&S[16384] + w * 1024, lane);
    stage(0, 0);

    for (int r = 0; r < 25; ++r) {
        asm volatile("s_waitcnt vmcnt(0)" ::: "memory");   // own stage(r) landed
        __builtin_amdgcn_s_barrier();                      // raw: no vmcnt(0) drain of others
        asm volatile("" ::: "memory");
        if (r + 1 < 25) stage(r + 1, (r + 1) & 1);         // flies during body(r)
        round_body(r, r & 1);
    }
    __syncthreads();                           // all waves done; LDS reusable

    // ---- merge 4 roles per q-half (two independent trees) ----
    float* mg = (float*)&S[0];
    {
        int slot = ((qh * 2 + (g & 1)) * 64 + lane) * 24;
        if (g >= 2) {
            *(f32x4*)&mg[slot + 0]  = o[0][0];
            *(f32x4*)&mg[slot + 4]  = o[0][1];
            *(f32x4*)&mg[slot + 8]  = o[1][0];
            *(f32x4*)&mg[slot + 12] = o[1][1];
            *(f32x4*)&mg[slot + 16] = lv[0];
            *(f32x4*)&mg[slot + 20] = lv[1];
        }
        __syncthreads();
        if (g < 2) {
            o[0][0] += *(const f32x4*)&mg[slot + 0];
            o[0][1] += *(const f32x4*)&mg[slot + 4];
            o[1][0] += *(const f32x4*)&mg[slot + 8];
            o[1][1] += *(const f32x4*)&mg[slot + 12];
            lv[0]   += *(const f32x4*)&mg[slot + 16];
            lv[1]   += *(const f32x4*)&mg[slot + 20];
        }
        __syncthreads();
    }
    {
        int slot = (qh * 64 + lane) * 24;
        if (g == 1) {
            *(f32x4*)&mg[slot + 0]  = o[0][0];
            *(f32x4*)&mg[slot + 4]  = o[0][1];
            *(f32x4*)&mg[slot + 8]  = o[1][0];
            *(f32x4*)&mg[slot + 12] = o[1][1];
            *(f32x4*)&mg[slot + 16] = lv[0];
            *(f32x4*)&mg[slot + 20] = lv[1];
        }
        __syncthreads();
        if (g == 0) {
            o[0][0] += *(const f32x4*)&mg[slot + 0];
            o[0][1] += *(const f32x4*)&mg[slot + 4];
            o[1][0] += *(const f32x4*)&mg[slot + 8];
            o[1][1] += *(const f32x4*)&mg[slot + 12];
            lv[0]   += *(const f32x4*)&mg[slot + 16];
            lv[1]   += *(const f32x4*)&mg[slot + 20];
            float gam = gammap[0];
#pragma unroll
            for (int i = 0; i < 2; ++i) {
#pragma unroll
                for (int r2 = 0; r2 < 4; ++r2) {
                    float scl = gam / lv[i][r2];
                    int q = blockIdx.y * 64 + qh * 32 + i * 16 + quad * 4 + r2;
                    size_t base = ((size_t)(b * SQ + q) << 8) + h * 32 + l16;
                    out[base]      = o[i][0][r2] * scl + x[base];
                    out[base + 16] = o[i][1][r2] * scl + x[base + 16];
                }
            }
        }
    }
}

// ---------------- launcher ----------------
extern "C" void kernel_launch(void* const* d_in, const int* in_sizes, int n_in,
                              void* d_out, int out_size, void* d_ws, size_t ws_size,
                              hipStream_t stream) {
    const float* x     = (const float*)d_in[0];
    const float* Wq    = (const float*)d_in[1];
    const float* bq    = (const float*)d_in[2];
    const float* Wk    = (const float*)d_in[3];
    const float* bk    = (const float*)d_in[4];
    const float* Wv    = (const float*)d_in[5];
    const float* bv    = (const float*)d_in[6];
    const float* gamma = (const float*)d_in[7];
    float* out = (float*)d_out;

    u16* ws   = (u16*)d_ws;
    u16* qbuf = ws + WS_Q;
    u16* kbuf = ws + WS_K;
    u16* vtb  = ws + WS_VT;
    u16* wtf  = ws + WS_WT;
    u16* crow = ws + WS_CB;
    u16* xb   = ws + WS_XB;

    xprep_kernel<<<784, 256, 0, stream>>>(x, xb);
    wprep_kernel<<<dim3(4, 4, 3), 256, 0, stream>>>(Wq, Wk, Wv, wtf, vtb, crow);
    proj_kernel<<<dim3(98, 3, 4), 256, 0, stream>>>(xb, wtf, bq, bk, bv, qbuf, kbuf, vtb);
    attn_kernel<<<dim3(16, 49), 512, 0, stream>>>(qbuf, kbuf, vtb, crow, x, gamma, out);
}

// Round 6
// 153.125 us; speedup vs baseline: 1.5420x; 1.5420x over previous
//
#include <hip/hip_runtime.h>

// ---------------- types / helpers ----------------
typedef unsigned short u16;
typedef float f32x4 __attribute__((ext_vector_type(4)));
typedef short bf16x8 __attribute__((ext_vector_type(8)));

__device__ __forceinline__ u16 f2bf(float f) {
    unsigned u = __float_as_uint(f);
    u = (u + 0x7FFFu + ((u >> 16) & 1u)) >> 16;
    return (u16)u;
}

#define LOG2E 1.4426950408889634f

#if __has_builtin(__builtin_amdgcn_exp2f)
__device__ __forceinline__ float exp2_fast(float x) { return __builtin_amdgcn_exp2f(x); }
#else
__device__ __forceinline__ float exp2_fast(float x) { return __expf(x * 0.6931471805599453f); }
#endif

__device__ __forceinline__ unsigned pack2bf(float a, float b) {
    unsigned ua = __float_as_uint(a) + 0x8000u;
    unsigned ub = __float_as_uint(b) + 0x8000u;
#if __has_builtin(__builtin_amdgcn_perm)
    return __builtin_amdgcn_perm(ub, ua, 0x07060302u);
#else
    return ((ua >> 16) & 0xFFFFu) | (ub & 0xFFFF0000u);
#endif
}

#if __has_builtin(__builtin_amdgcn_cvt_pk_bf16_f32)
typedef __bf16 bf2_t __attribute__((ext_vector_type(2)));
__device__ __forceinline__ unsigned cvtpk(float a, float b) {
    bf2_t r = __builtin_amdgcn_cvt_pk_bf16_f32(a, b);
    return __builtin_bit_cast(unsigned, r);
}
#else
__device__ __forceinline__ unsigned cvtpk(float a, float b) { return pack2bf(a, b); }
#endif

__device__ __forceinline__ bf16x8 bc8(uint4 u) { return __builtin_bit_cast(bf16x8, u); }

// async 16B/lane global->LDS DMA; lds dst = wave-uniform base + lane*16.
#if __has_builtin(__builtin_amdgcn_global_load_lds)
typedef const __attribute__((address_space(1))) void* as1cv;
typedef __attribute__((address_space(3))) void* as3v;
__device__ __forceinline__ void dma16(const void* g, void* lds_base, int lane) {
    __builtin_amdgcn_global_load_lds((as1cv)g, (as3v)lds_base, 16, 0, 0);
}
#else
__device__ __forceinline__ void dma16(const void* g, void* lds_base, int lane) {
    *(uint4*)((char*)lds_base + lane * 16) = *(const uint4*)g;
}
#endif

// Problem constants. DEDUP: reflect-pad duplicates keys; only 3136 unique source
// pixels. Multiplicity c in {1,2,4} folded into DATA (V pre-scaled, counts row).
#define BB 2
#define HH 56
#define SQ 3136
#define SKP 3200
#define VT_STRIDE 3200
#define CROWN 3584

// workspace offsets (u16 units)
#define WS_Q    0         // 6272*256
#define WS_K    1605632   // 6272*256
#define WS_VT   3211264   // 512*3200
#define WS_WT   4849664   // 3*65536 fragment-packed weights
#define WS_CB   5046272   // 3584 u16: bf16 counts row

// ---------------- kernel 0: weight fragment-pack + crow + VT pad zero -------------
// wtf[mode][f=((nz*8+s)*8+nt)][L=quad*16+l16][j=0..7]
//   = W_mode[k=s*32+quad*8+j][d=nz*128+nt*16+l16] * (mode==0 ? LOG2E : 1)
__global__ __launch_bounds__(256) void wprep_kernel(const float* __restrict__ Wq,
                                                    const float* __restrict__ Wk,
                                                    const float* __restrict__ Wv,
                                                    u16* __restrict__ wtf,
                                                    u16* __restrict__ vtb,
                                                    u16* __restrict__ crow) {
    __shared__ u16 T[64][68];
    int mode = blockIdx.z;
    const float* W = (mode == 0) ? Wq : ((mode == 1) ? Wk : Wv);
    float sc = (mode == 0) ? LOG2E : 1.0f;
    int kx = blockIdx.x * 64, dx = blockIdx.y * 64;
    int tid = threadIdx.x;
    int r16 = tid >> 4, c4 = (tid & 15) * 4;
#pragma unroll
    for (int p = 0; p < 4; ++p) {
        int kr = p * 16 + r16;
        float4 f = *(const float4*)&W[(size_t)(kx + kr) * 256 + dx + c4];
        T[kr][c4 + 0] = f2bf(f.x * sc);
        T[kr][c4 + 1] = f2bf(f.y * sc);
        T[kr][c4 + 2] = f2bf(f.z * sc);
        T[kr][c4 + 3] = f2bf(f.w * sc);
    }
    __syncthreads();
    int l16 = tid & 15, nt_loc = (tid >> 4) & 3, quad = (tid >> 6) & 3;
#pragma unroll
    for (int s_loc = 0; s_loc < 2; ++s_loc) {
        int k0 = s_loc * 32 + quad * 8;
        int d_loc = nt_loc * 16 + l16;
        u16 tmp[8];
#pragma unroll
        for (int j = 0; j < 8; ++j) tmp[j] = T[k0 + j][d_loc];
        int d = dx + d_loc;
        int nz = d >> 7, ntg = (d >> 4) & 7;
        int s = (kx >> 5) + s_loc;
        int f = (nz * 8 + s) * 8 + ntg;
        int L = quad * 16 + l16;
        *(uint4*)&wtf[(size_t)mode * 65536 + (size_t)f * 512 + (size_t)L * 8] = *(uint4*)tmp;
    }
    if (mode == 1 && kx == 0 && dx == 0) {
        for (int i = tid; i < CROWN; i += 256) {
            u16 v = 0;
            if (i < SQ) {
                int rr = i / 56, cc = i - rr * 56;
                int mr = (((rr >= 1) && (rr <= 3)) || ((rr >= 52) && (rr <= 54))) ? 2 : 1;
                int mc = (((cc >= 1) && (cc <= 3)) || ((cc >= 52) && (cc <= 54))) ? 2 : 1;
                int prod = mr * mc;
                v = (prod == 1) ? (u16)0x3F80 : ((prod == 2) ? (u16)0x4000 : (u16)0x4080);
            }
            crow[i] = v;
        }
    }
    if (mode == 2 && kx == 0 && dx == 0) {
        for (int i = tid; i < 512 * 8; i += 256) {
            int row = i >> 3, c16 = i & 7;
            *(uint4*)&vtb[(size_t)row * VT_STRIDE + SQ + c16 * 8] = (uint4){0, 0, 0, 0};
        }
    }
}

// ---------------- kernel 1: projections (round-4 proven version) -------------------
// grid (98, 3 modes, 2 nz). modes 0/1 (Q/K): swapped MFMA operands -> row-major
// per-lane output -> packed uint2 stores. mode 2: V^T stores pre-scaled by c.
__global__ __launch_bounds__(256, 4) void proj_kernel(const float* __restrict__ x,
                                                      const u16* __restrict__ wtf,
                                                      const float* __restrict__ bq,
                                                      const float* __restrict__ bk,
                                                      const float* __restrict__ bv,
                                                      u16* __restrict__ qout,
                                                      u16* __restrict__ kout,
                                                      u16* __restrict__ vtout) {
    int mode = blockIdx.y, nz = blockIdx.z;
    int mbase = blockIdx.x * 64;
    int tid = threadIdx.x;
    int wave = tid >> 6, quad = (tid >> 4) & 3, l16 = tid & 15;
    const float* bias = (mode == 0) ? bq : ((mode == 1) ? bk : bv);
    float wsc = (mode == 0) ? LOG2E : 1.0f;
    const u16* wf = wtf + (size_t)mode * 65536 + (size_t)nz * 32768 + (size_t)(quad * 16 + l16) * 8;

    int m_a = mbase + wave * 16 + l16;
    const float* xr = x + (size_t)m_a * 256;

    f32x4 acc[8];
#pragma unroll
    for (int i = 0; i < 8; i++) acc[i] = (f32x4){0.f, 0.f, 0.f, 0.f};

#pragma unroll
    for (int s = 0; s < 8; ++s) {
        float4 f0 = *(const float4*)&xr[s * 32 + quad * 8];
        float4 f1 = *(const float4*)&xr[s * 32 + quad * 8 + 4];
        uint4 aw = (uint4){pack2bf(f0.x, f0.y), pack2bf(f0.z, f0.w),
                           pack2bf(f1.x, f1.y), pack2bf(f1.z, f1.w)};
        bf16x8 af = bc8(aw);
        if (mode == 2) {
#pragma unroll
            for (int nt = 0; nt < 8; nt++) {
                bf16x8 bfrag = *(const bf16x8*)&wf[(s * 8 + nt) * 512];
                acc[nt] = __builtin_amdgcn_mfma_f32_16x16x32_bf16(af, bfrag, acc[nt], 0, 0, 0);
            }
        } else {
#pragma unroll
            for (int nt = 0; nt < 8; nt++) {
                bf16x8 bfrag = *(const bf16x8*)&wf[(s * 8 + nt) * 512];
                acc[nt] = __builtin_amdgcn_mfma_f32_16x16x32_bf16(bfrag, af, acc[nt], 0, 0, 0);
            }
        }
    }

    if (mode == 2) {
        int mrow_base = mbase + wave * 16 + quad * 4;
        float mult[4];
#pragma unroll
        for (int p = 0; p < 4; ++p) {
            int m = mrow_base + p;
            int kp = (m >= SQ) ? m - SQ : m;
            int rr = kp / 56, cc = kp - rr * 56;
            float mr = (((rr >= 1) && (rr <= 3)) || ((rr >= 52) && (rr <= 54))) ? 2.f : 1.f;
            float mc = (((cc >= 1) && (cc <= 3)) || ((cc >= 52) && (cc <= 54))) ? 2.f : 1.f;
            mult[p] = mr * mc;
        }
#pragma unroll
        for (int nt = 0; nt < 8; nt++) {
            int c = nz * 128 + nt * 16 + l16;
            float bvv = bias[c];
#pragma unroll
            for (int p = 0; p < 4; p += 2) {
                int m = mrow_base + p;
                int bb = (m >= SQ) ? 1 : 0;
                int kp = m - bb * SQ;
                unsigned pk = pack2bf((acc[nt][p] + bvv) * mult[p],
                                      (acc[nt][p + 1] + bvv) * mult[p + 1]);
                *(unsigned*)&vtout[(size_t)(bb * 256 + c) * VT_STRIDE + kp] = pk;
            }
        }
    } else {
        u16* outp = (mode == 0) ? qout : kout;
#pragma unroll
        for (int nt = 0; nt < 8; nt++) {
            int c0 = nz * 128 + nt * 16 + quad * 4;
            float4 b4 = *(const float4*)&bias[c0];
            float v0 = acc[nt][0] + b4.x * wsc;
            float v1 = acc[nt][1] + b4.y * wsc;
            float v2 = acc[nt][2] + b4.z * wsc;
            float v3 = acc[nt][3] + b4.w * wsc;
            uint2 pk = (uint2){pack2bf(v0, v1), pack2bf(v2, v3)};
            *(uint2*)&outp[((size_t)m_a << 8) + c0] = pk;
        }
    }
}

// ---------------- kernel 2: flash attention (8 waves, 84-reg budget, no spills) ----
// grid (16 bh, 49 qsub), 512 thr = 8 waves = 2 q-halves x 4 key-roles.
// launch_bounds(512,6): 84 unified regs/wave (round-5's (512,8)=64 spilled ->
// 56MB scratch traffic). 6 waves/EU = 24 waves/CU = 3 blocks/CU; grid 784 ->
// 768 resident + 16-block tail. round_body split into tile-A pass then tile-B
// pass to keep peak register demand ~72. Raw s_barrier + own vmcnt(0) per round.
__global__ __launch_bounds__(512, 6) void attn_kernel(const u16* __restrict__ qb,
                                                      const u16* __restrict__ kb,
                                                      const u16* __restrict__ vtb,
                                                      const u16* __restrict__ crow,
                                                      const float* __restrict__ x,
                                                      const float* __restrict__ gammap,
                                                      float* __restrict__ out) {
    __shared__ __align__(16) u16 S[19968];   // 2 bufs x 8192 (K 4096 + V 4096), cnt @16384

    int tid = threadIdx.x;
    int w = tid >> 6, lane = tid & 63, quad = lane >> 4, l16 = lane & 15;
    int g = w & 3, qh = w >> 2;
    int bh = blockIdx.x;
    int b = bh >> 3, h = bh & 7;
    int qbase = b * SQ + blockIdx.y * 64 + qh * 32;

    bf16x8 qf[2];
#pragma unroll
    for (int i = 0; i < 2; ++i)
        qf[i] = *(const bf16x8*)&qb[((size_t)(qbase + i * 16 + l16) << 8) + h * 32 + quad * 8];

    const u16* kg = kb + ((size_t)(b * SQ) << 8) + h * 32;
    const u16* vg = vtb + (size_t)(b * 256 + h * 32) * VT_STRIDE;

    f32x4 o[2][2], lv[2];
#pragma unroll
    for (int i = 0; i < 2; ++i) {
        o[i][0] = (f32x4){0.f, 0.f, 0.f, 0.f};
        o[i][1] = (f32x4){0.f, 0.f, 0.f, 0.f};
        lv[i]   = (f32x4){0.f, 0.f, 0.f, 0.f};
    }

    // wave w stages K tile w and V group w (2 DMAs/round)
    auto stage = [&](int r_ch, int buf) {
        u16* base = &S[buf * 8192];
        int kbase = r_ch * 128;
        int grow = kbase + w * 16 + l16;
        if (grow > SQ - 1) grow = SQ - 1;
        dma16(kg + ((size_t)grow << 8) + (lane >> 4) * 8, base + w * 512, lane);
        int col = kbase + (2 * w + (lane >> 5)) * 8;
        dma16(vg + (size_t)(lane & 31) * VT_STRIDE + col, base + 4096 + w * 512, lane);
    };

    int tA = g, tB = g + 4;
    int vOffA = tA * 512 + (((quad >> 1) * 32 + l16) << 3) + (quad & 1) * 4;
    int vOffB = tB * 512 + (((quad >> 1) * 32 + l16) << 3) + (quad & 1) * 4;

    auto round_body = [&](int r, int bR) {
        const u16* Kl = &S[bR * 8192];
        const u16* Vl = Kl + 4096;
        const u16* cnt = &S[16384] + r * 128;
        f32x4 z = (f32x4){0.f, 0.f, 0.f, 0.f};

        // ---- tile A: QK + exp (then release eA) ----
        float pA[2][4];
        {
            bf16x8 kfA = *(const bf16x8*)&Kl[tA * 512 + lane * 8];
            f32x4 eA0 = __builtin_amdgcn_mfma_f32_16x16x32_bf16(kfA, qf[0], z, 0, 0, 0);
            f32x4 eA1 = __builtin_amdgcn_mfma_f32_16x16x32_bf16(kfA, qf[1], z, 0, 0, 0);
#pragma unroll
            for (int j = 0; j < 4; ++j) pA[0][j] = exp2_fast(eA0[j]);
#pragma unroll
            for (int j = 0; j < 4; ++j) pA[1][j] = exp2_fast(eA1[j]);
        }
        // ---- tile B: QK + exp ----
        float pB[2][4];
        {
            bf16x8 kfB = *(const bf16x8*)&Kl[tB * 512 + lane * 8];
            f32x4 eB0 = __builtin_amdgcn_mfma_f32_16x16x32_bf16(kfB, qf[0], z, 0, 0, 0);
            f32x4 eB1 = __builtin_amdgcn_mfma_f32_16x16x32_bf16(kfB, qf[1], z, 0, 0, 0);
#pragma unroll
            for (int j = 0; j < 4; ++j) pB[0][j] = exp2_fast(eB0[j]);
#pragma unroll
            for (int j = 0; j < 4; ++j) pB[1][j] = exp2_fast(eB1[j]);
        }
        // ---- PV (K=32 packs tiles A+B) ----
        uint2 ca = *(const uint2*)&cnt[tA * 16 + quad * 4];
        uint2 cc = *(const uint2*)&cnt[tB * 16 + quad * 4];
        bf16x8 cf = bc8((uint4){ca.x, ca.y, cc.x, cc.y});
        uint2 wA0 = *(const uint2*)&Vl[vOffA];
        uint2 wB0 = *(const uint2*)&Vl[vOffB];
        bf16x8 V0 = bc8((uint4){wA0.x, wA0.y, wB0.x, wB0.y});
        uint2 wA1 = *(const uint2*)&Vl[vOffA + 128];
        uint2 wB1 = *(const uint2*)&Vl[vOffB + 128];
        bf16x8 V1 = bc8((uint4){wA1.x, wA1.y, wB1.x, wB1.y});

#pragma unroll
        for (int i = 0; i < 2; ++i) {
            bf16x8 pa = bc8((uint4){cvtpk(pA[i][0], pA[i][1]), cvtpk(pA[i][2], pA[i][3]),
                                    cvtpk(pB[i][0], pB[i][1]), cvtpk(pB[i][2], pB[i][3])});
            o[i][0] = __builtin_amdgcn_mfma_f32_16x16x32_bf16(pa, V0, o[i][0], 0, 0, 0);
            o[i][1] = __builtin_amdgcn_mfma_f32_16x16x32_bf16(pa, V1, o[i][1], 0, 0, 0);
            lv[i]   = __builtin_amdgcn_mfma_f32_16x16x32_bf16(pa, cf, lv[i], 0, 0, 0);
        }
    };

    // prologue: counts (7 x 1KB across waves 0-6) + round 0
    if (w < 7) dma16(crow + w * 512 + lane * 8, (char*)&S[16384] + w * 1024, lane);
    stage(0, 0);

    for (int r = 0; r < 25; ++r) {
        asm volatile("s_waitcnt vmcnt(0)" ::: "memory");   // own stage(r) landed
        __builtin_amdgcn_s_barrier();                      // raw: others' prefetch stays in flight
        asm volatile("" ::: "memory");
        if (r + 1 < 25) stage(r + 1, (r + 1) & 1);         // flies during body(r)
        round_body(r, r & 1);
    }
    __syncthreads();                           // all waves done; LDS reusable

    // ---- merge 4 roles per q-half (two independent trees) ----
    float* mg = (float*)&S[0];
    {
        int slot = ((qh * 2 + (g & 1)) * 64 + lane) * 24;
        if (g >= 2) {
            *(f32x4*)&mg[slot + 0]  = o[0][0];
            *(f32x4*)&mg[slot + 4]  = o[0][1];
            *(f32x4*)&mg[slot + 8]  = o[1][0];
            *(f32x4*)&mg[slot + 12] = o[1][1];
            *(f32x4*)&mg[slot + 16] = lv[0];
            *(f32x4*)&mg[slot + 20] = lv[1];
        }
        __syncthreads();
        if (g < 2) {
            o[0][0] += *(const f32x4*)&mg[slot + 0];
            o[0][1] += *(const f32x4*)&mg[slot + 4];
            o[1][0] += *(const f32x4*)&mg[slot + 8];
            o[1][1] += *(const f32x4*)&mg[slot + 12];
            lv[0]   += *(const f32x4*)&mg[slot + 16];
            lv[1]   += *(const f32x4*)&mg[slot + 20];
        }
        __syncthreads();
    }
    {
        int slot = (qh * 64 + lane) * 24;
        if (g == 1) {
            *(f32x4*)&mg[slot + 0]  = o[0][0];
            *(f32x4*)&mg[slot + 4]  = o[0][1];
            *(f32x4*)&mg[slot + 8]  = o[1][0];
            *(f32x4*)&mg[slot + 12] = o[1][1];
            *(f32x4*)&mg[slot + 16] = lv[0];
            *(f32x4*)&mg[slot + 20] = lv[1];
        }
        __syncthreads();
        if (g == 0) {
            o[0][0] += *(const f32x4*)&mg[slot + 0];
            o[0][1] += *(const f32x4*)&mg[slot + 4];
            o[1][0] += *(const f32x4*)&mg[slot + 8];
            o[1][1] += *(const f32x4*)&mg[slot + 12];
            lv[0]   += *(const f32x4*)&mg[slot + 16];
            lv[1]   += *(const f32x4*)&mg[slot + 20];
            float gam = gammap[0];
#pragma unroll
            for (int i = 0; i < 2; ++i) {
#pragma unroll
                for (int r2 = 0; r2 < 4; ++r2) {
                    float scl = gam / lv[i][r2];
                    int q = blockIdx.y * 64 + qh * 32 + i * 16 + quad * 4 + r2;
                    size_t base = ((size_t)(b * SQ + q) << 8) + h * 32 + l16;
                    out[base]      = o[i][0][r2] * scl + x[base];
                    out[base + 16] = o[i][1][r2] * scl + x[base + 16];
                }
            }
        }
    }
}

// ---------------- launcher ----------------
extern "C" void kernel_launch(void* const* d_in, const int* in_sizes, int n_in,
                              void* d_out, int out_size, void* d_ws, size_t ws_size,
                              hipStream_t stream) {
    const float* x     = (const float*)d_in[0];
    const float* Wq    = (const float*)d_in[1];
    const float* bq    = (const float*)d_in[2];
    const float* Wk    = (const float*)d_in[3];
    const float* bk    = (const float*)d_in[4];
    const float* Wv    = (const float*)d_in[5];
    const float* bv    = (const float*)d_in[6];
    const float* gamma = (const float*)d_in[7];
    float* out = (float*)d_out;

    u16* ws   = (u16*)d_ws;
    u16* qbuf = ws + WS_Q;
    u16* kbuf = ws + WS_K;
    u16* vtb  = ws + WS_VT;
    u16* wtf  = ws + WS_WT;
    u16* crow = ws + WS_CB;

    wprep_kernel<<<dim3(4, 4, 3), 256, 0, stream>>>(Wq, Wk, Wv, wtf, vtb, crow);
    proj_kernel<<<dim3(98, 3, 2), 256, 0, stream>>>(x, wtf, bq, bk, bv, qbuf, kbuf, vtb);
    attn_kernel<<<dim3(16, 49), 512, 0, stream>>>(qbuf, kbuf, vtb, crow, x, gamma, out);
}

// Round 7
// 134.776 us; speedup vs baseline: 1.7520x; 1.1361x over previous
//
#include <hip/hip_runtime.h>

// ---------------- types / helpers ----------------
typedef unsigned short u16;
typedef float f32x4 __attribute__((ext_vector_type(4)));
typedef short bf16x8 __attribute__((ext_vector_type(8)));

__device__ __forceinline__ u16 f2bf(float f) {
    unsigned u = __float_as_uint(f);
    u = (u + 0x7FFFu + ((u >> 16) & 1u)) >> 16;
    return (u16)u;
}

#define LOG2E 1.4426950408889634f

#if __has_builtin(__builtin_amdgcn_exp2f)
__device__ __forceinline__ float exp2_fast(float x) { return __builtin_amdgcn_exp2f(x); }
#else
__device__ __forceinline__ float exp2_fast(float x) { return __expf(x * 0.6931471805599453f); }
#endif

__device__ __forceinline__ unsigned pack2bf(float a, float b) {
    unsigned ua = __float_as_uint(a) + 0x8000u;
    unsigned ub = __float_as_uint(b) + 0x8000u;
#if __has_builtin(__builtin_amdgcn_perm)
    return __builtin_amdgcn_perm(ub, ua, 0x07060302u);
#else
    return ((ua >> 16) & 0xFFFFu) | (ub & 0xFFFF0000u);
#endif
}

#if __has_builtin(__builtin_amdgcn_cvt_pk_bf16_f32)
typedef __bf16 bf2_t __attribute__((ext_vector_type(2)));
__device__ __forceinline__ unsigned cvtpk(float a, float b) {
    bf2_t r = __builtin_amdgcn_cvt_pk_bf16_f32(a, b);
    return __builtin_bit_cast(unsigned, r);
}
#else
__device__ __forceinline__ unsigned cvtpk(float a, float b) { return pack2bf(a, b); }
#endif

__device__ __forceinline__ bf16x8 bc8(uint4 u) { return __builtin_bit_cast(bf16x8, u); }

// async 16B/lane global->LDS DMA; lds dst = wave-uniform base + lane*16.
#if __has_builtin(__builtin_amdgcn_global_load_lds)
typedef const __attribute__((address_space(1))) void* as1cv;
typedef __attribute__((address_space(3))) void* as3v;
__device__ __forceinline__ void dma16(const void* g, void* lds_base, int lane) {
    __builtin_amdgcn_global_load_lds((as1cv)g, (as3v)lds_base, 16, 0, 0);
}
#else
__device__ __forceinline__ void dma16(const void* g, void* lds_base, int lane) {
    *(uint4*)((char*)lds_base + lane * 16) = *(const uint4*)g;
}
#endif

// Problem constants. DEDUP: only 3136 unique keys; multiplicity {1,2,4} folded
// into V (pre-scaled) + counts row. ALL intermediate layouts are 16-row fragment
// TILES [tile][s][lane][16B] so every global access (proj loads/stores, attn
// Q loads, attn K/V DMAs) is CONTIGUOUS per wave — no large-stride scatter.
#define BB 2
#define HH 56
#define SQ 3136
#define CROWN 3584

// workspace offsets (u16 units); total 6,688,256 u16 = 13.38 MB
#define WS_Q    0         // 392 tiles * 4096
#define WS_K    1605632   // 2 b * 200 tiles * 4096 (196 real + 4 pad)
#define WS_V    3244032   // 16 bh * 200 rg * 512
#define WS_WT   4882432   // 3*65536 fragment-packed weights
#define WS_CB   5079040   // 3584 u16 bf16 counts
#define WS_XB   5082624   // 392 tiles * 4096 bf16 x

// ---------------- kernel A: x -> bf16 fragment tiles (both sides coalesced) --------
// xbf[t][s][L][j] = bf16( x[t*16 + (L&15)][s*32 + (L>>4)*8 + j] )
__global__ __launch_bounds__(256) void xprep_kernel(const float* __restrict__ x,
                                                    u16* __restrict__ xbf) {
    __shared__ float T[16][256];
    int tile = blockIdx.x, tid = threadIdx.x;
    int r = tid >> 4, c0 = (tid & 15) * 16;
    const float* src = x + ((size_t)tile * 16 + r) * 256 + c0;
#pragma unroll
    for (int k = 0; k < 4; ++k)
        *(float4*)&T[r][c0 + k * 4] = *(const float4*)&src[k * 4];
    __syncthreads();
#pragma unroll
    for (int e = 0; e < 2; ++e) {
        int g = tid + e * 256;                  // granule 0..511
        int s = g >> 6, L = g & 63;
        const float* row = &T[L & 15][s * 32 + (L >> 4) * 8];
        uint4 pk = (uint4){pack2bf(row[0], row[1]), pack2bf(row[2], row[3]),
                           pack2bf(row[4], row[5]), pack2bf(row[6], row[7])};
        *(uint4*)&xbf[(size_t)tile * 4096 + (size_t)g * 8] = pk;
    }
}

// ---------------- kernel 0: weight fragment-pack + crow + K/V pad-tile zero --------
__global__ __launch_bounds__(256) void wprep_kernel(const float* __restrict__ Wq,
                                                    const float* __restrict__ Wk,
                                                    const float* __restrict__ Wv,
                                                    u16* __restrict__ wtf,
                                                    u16* __restrict__ kbf,
                                                    u16* __restrict__ vbf,
                                                    u16* __restrict__ crow) {
    __shared__ u16 T[64][68];
    int mode = blockIdx.z;
    const float* W = (mode == 0) ? Wq : ((mode == 1) ? Wk : Wv);
    float sc = (mode == 0) ? LOG2E : 1.0f;
    int kx = blockIdx.x * 64, dx = blockIdx.y * 64;
    int tid = threadIdx.x;
    int r16 = tid >> 4, c4 = (tid & 15) * 4;
#pragma unroll
    for (int p = 0; p < 4; ++p) {
        int kr = p * 16 + r16;
        float4 f = *(const float4*)&W[(size_t)(kx + kr) * 256 + dx + c4];
        T[kr][c4 + 0] = f2bf(f.x * sc);
        T[kr][c4 + 1] = f2bf(f.y * sc);
        T[kr][c4 + 2] = f2bf(f.z * sc);
        T[kr][c4 + 3] = f2bf(f.w * sc);
    }
    __syncthreads();
    int l16 = tid & 15, nt_loc = (tid >> 4) & 3, quad = (tid >> 6) & 3;
#pragma unroll
    for (int s_loc = 0; s_loc < 2; ++s_loc) {
        int k0 = s_loc * 32 + quad * 8;
        int d_loc = nt_loc * 16 + l16;
        u16 tmp[8];
#pragma unroll
        for (int j = 0; j < 8; ++j) tmp[j] = T[k0 + j][d_loc];
        int d = dx + d_loc;
        int nz = d >> 7, ntg = (d >> 4) & 7;
        int s = (kx >> 5) + s_loc;
        int f = (nz * 8 + s) * 8 + ntg;
        int L = quad * 16 + l16;
        *(uint4*)&wtf[(size_t)mode * 65536 + (size_t)f * 512 + (size_t)L * 8] = *(uint4*)tmp;
    }
    uint4 z4 = (uint4){0, 0, 0, 0};
    if (mode == 0 && kx == 0 && dx == 0) {
        // zero K pad tiles 196..199 per b
        for (int i = tid; i < 4096; i += 256) {
            int bb = i >> 11, rem = i & 2047;
            int t = 196 + (rem >> 9), off = (rem & 511) * 8;
            *(uint4*)&kbf[(((size_t)(bb * 200 + t)) << 12) + off] = z4;
        }
    }
    if (mode == 1 && kx == 0 && dx == 0) {
        for (int i = tid; i < CROWN; i += 256) {
            u16 v = 0;
            if (i < SQ) {
                int rr = i / 56, cc = i - rr * 56;
                int mr = (((rr >= 1) && (rr <= 3)) || ((rr >= 52) && (rr <= 54))) ? 2 : 1;
                int mc = (((cc >= 1) && (cc <= 3)) || ((cc >= 52) && (cc <= 54))) ? 2 : 1;
                int prod = mr * mc;
                v = (prod == 1) ? (u16)0x3F80 : ((prod == 2) ? (u16)0x4000 : (u16)0x4080);
            }
            crow[i] = v;
        }
    }
    if (mode == 2 && kx == 0 && dx == 0) {
        // zero V pad tiles rg 196..199 per (b,h)
        for (int i = tid; i < 4096; i += 256) {
            int bh = i >> 8, rem = i & 255;
            int rgp = 196 + (rem >> 6), off = (rem & 63) * 8;
            *(uint4*)&vbf[(((size_t)(bh * 200 + rgp)) << 9) + off] = z4;
        }
    }
}

// ---------------- kernel 1: projections (all loads AND stores contiguous) ----------
// grid (98, 3 modes, 2 nz). A from xbf tiles (1KB linear/wave-step); B from wtf
// (1KB linear); stores land in fragment tiles as full 512B contiguous blocks.
__global__ __launch_bounds__(256, 4) void proj_kernel(const u16* __restrict__ xbf,
                                                      const u16* __restrict__ wtf,
                                                      const float* __restrict__ bq,
                                                      const float* __restrict__ bk,
                                                      const float* __restrict__ bv,
                                                      u16* __restrict__ qbf,
                                                      u16* __restrict__ kbf,
                                                      u16* __restrict__ vbf) {
    int mode = blockIdx.y, nz = blockIdx.z;
    int mbase = blockIdx.x * 64;
    int tid = threadIdx.x;
    int wave = tid >> 6, lane = tid & 63, quad = (tid >> 4) & 3, l16 = tid & 15;
    const float* bias = (mode == 0) ? bq : ((mode == 1) ? bk : bv);
    float wsc = (mode == 0) ? LOG2E : 1.0f;
    const u16* wf = wtf + (size_t)mode * 65536 + (size_t)nz * 32768 + (size_t)lane * 8;
    const u16* xt = xbf + (((size_t)(mbase >> 4) + wave) << 12);   // tile base (*4096)

    f32x4 acc[8];
#pragma unroll
    for (int i = 0; i < 8; i++) acc[i] = (f32x4){0.f, 0.f, 0.f, 0.f};

#pragma unroll
    for (int s = 0; s < 8; ++s) {
        bf16x8 af = *(const bf16x8*)&xt[(s << 9) + lane * 8];
        if (mode == 2) {
#pragma unroll
            for (int nt = 0; nt < 8; nt++) {
                bf16x8 bfrag = *(const bf16x8*)&wf[(s * 8 + nt) * 512];
                acc[nt] = __builtin_amdgcn_mfma_f32_16x16x32_bf16(af, bfrag, acc[nt], 0, 0, 0);
            }
        } else {
#pragma unroll
            for (int nt = 0; nt < 8; nt++) {
                bf16x8 bfrag = *(const bf16x8*)&wf[(s * 8 + nt) * 512];
                acc[nt] = __builtin_amdgcn_mfma_f32_16x16x32_bf16(bfrag, af, acc[nt], 0, 0, 0);
            }
        }
    }

    if (mode == 2) {
        // thread: d-channel c = nz*128+nt*16+l16, keys kp0..+3
        int b_ = (mbase >= SQ) ? 1 : 0;
        int kp0 = mbase - b_ * SQ + wave * 16 + quad * 4;
        int rg = (mbase - b_ * SQ + wave * 16) >> 4;
        float mult[4];
#pragma unroll
        for (int p = 0; p < 4; ++p) {
            int kp = kp0 + p;
            int rr = kp / 56, cc = kp - rr * 56;
            float mr = (((rr >= 1) && (rr <= 3)) || ((rr >= 52) && (rr <= 54))) ? 2.f : 1.f;
            float mc = (((cc >= 1) && (cc <= 3)) || ((cc >= 52) && (cc <= 54))) ? 2.f : 1.f;
            mult[p] = mr * mc;
        }
#pragma unroll
        for (int nt = 0; nt < 8; nt++) {
            int c = nz * 128 + nt * 16 + l16;
            float bvv = bias[c];
            int h_idx = nz * 4 + (nt >> 1);
            int L = (nt & 1) * 16 + l16 + ((quad >> 1) & 1) * 32;
            float va0 = (acc[nt][0] + bvv) * mult[0];
            float va1 = (acc[nt][1] + bvv) * mult[1];
            float va2 = (acc[nt][2] + bvv) * mult[2];
            float va3 = (acc[nt][3] + bvv) * mult[3];
            uint2 pk = (uint2){pack2bf(va0, va1), pack2bf(va2, va3)};
            *(uint2*)&vbf[(((size_t)((b_ * 8 + h_idx) * 200 + rg)) << 9) + L * 8 + (quad & 1) * 4] = pk;
        }
    } else {
        // thread: row m_a = mbase+wave*16+l16, channels c0..+3 per nt
        u16* outp = (mode == 0) ? qbf : kbf;
        int t = (mbase >> 4) + wave;
        int tt = (mode == 0) ? t : (t + (t >= 196 ? 4 : 0));   // kbf has 4 pad tiles per b
#pragma unroll
        for (int nt = 0; nt < 8; nt++) {
            int c0 = nz * 128 + nt * 16 + quad * 4;
            float4 b4 = *(const float4*)&bias[c0];
            float v0 = acc[nt][0] + b4.x * wsc;
            float v1 = acc[nt][1] + b4.y * wsc;
            float v2 = acc[nt][2] + b4.z * wsc;
            float v3 = acc[nt][3] + b4.w * wsc;
            int s_idx = nz * 4 + (nt >> 1);
            int Lrow = ((nt & 1) * 2 + (quad >> 1)) * 16 + l16;
            uint2 pk = (uint2){pack2bf(v0, v1), pack2bf(v2, v3)};
            *(uint2*)&outp[(((size_t)(tt * 8 + s_idx)) << 9) + Lrow * 8 + (quad & 1) * 4] = pk;
        }
    }
}

// ---------------- kernel 2: flash attention (round-6 structure, LINEAR DMAs) -------
// grid (16 bh, 49 qsub), 512 thr = 8 waves = 2 q-halves x 4 key-roles.
// K/V/Q now tile-packed: every DMA & Q load is a contiguous 1KB wave transaction.
__global__ __launch_bounds__(512, 6) void attn_kernel(const u16* __restrict__ qb,
                                                      const u16* __restrict__ kb,
                                                      const u16* __restrict__ vtb,
                                                      const u16* __restrict__ crow,
                                                      const float* __restrict__ x,
                                                      const float* __restrict__ gammap,
                                                      float* __restrict__ out) {
    __shared__ __align__(16) u16 S[19968];   // 2 bufs x 8192 (K 4096 + V 4096), cnt @16384

    int tid = threadIdx.x;
    int w = tid >> 6, lane = tid & 63, quad = lane >> 4, l16 = lane & 15;
    int g = w & 3, qh = w >> 2;
    int bh = blockIdx.x;
    int b = bh >> 3, h = bh & 7;

    int qtile = b * 196 + blockIdx.y * 4 + qh * 2;
    bf16x8 qf[2];
#pragma unroll
    for (int i = 0; i < 2; ++i)
        qf[i] = *(const bf16x8*)&qb[(((size_t)(qtile + i) * 8 + h) << 9) + lane * 8];

    const u16* kg = kb + ((size_t)(b * 200) << 12);             // b's K tile base
    const u16* vg = vtb + (((size_t)((b * 8 + h) * 200)) << 9); // (b,h) V tile base

    f32x4 o[2][2], lv[2];
#pragma unroll
    for (int i = 0; i < 2; ++i) {
        o[i][0] = (f32x4){0.f, 0.f, 0.f, 0.f};
        o[i][1] = (f32x4){0.f, 0.f, 0.f, 0.f};
        lv[i]   = (f32x4){0.f, 0.f, 0.f, 0.f};
    }

    // wave w stages K tile w and V tile w of chunk r_ch: both 1KB LINEAR
    auto stage = [&](int r_ch, int buf) {
        u16* base = &S[buf * 8192];
        int rg = r_ch * 8 + w;
        dma16(kg + (((size_t)rg * 8 + h) << 9) + lane * 8, base + w * 512, lane);
        dma16(vg + (((size_t)rg) << 9) + lane * 8, base + 4096 + w * 512, lane);
    };

    int tA = g, tB = g + 4;
    int vOffA = tA * 512 + (((quad >> 1) * 32 + l16) << 3) + (quad & 1) * 4;
    int vOffB = tB * 512 + (((quad >> 1) * 32 + l16) << 3) + (quad & 1) * 4;

    auto round_body = [&](int r, int bR) {
        const u16* Kl = &S[bR * 8192];
        const u16* Vl = Kl + 4096;
        const u16* cnt = &S[16384] + r * 128;
        f32x4 z = (f32x4){0.f, 0.f, 0.f, 0.f};

        float pA[2][4];
        {
            bf16x8 kfA = *(const bf16x8*)&Kl[tA * 512 + lane * 8];
            f32x4 eA0 = __builtin_amdgcn_mfma_f32_16x16x32_bf16(kfA, qf[0], z, 0, 0, 0);
            f32x4 eA1 = __builtin_amdgcn_mfma_f32_16x16x32_bf16(kfA, qf[1], z, 0, 0, 0);
#pragma unroll
            for (int j = 0; j < 4; ++j) pA[0][j] = exp2_fast(eA0[j]);
#pragma unroll
            for (int j = 0; j < 4; ++j) pA[1][j] = exp2_fast(eA1[j]);
        }
        float pB[2][4];
        {
            bf16x8 kfB = *(const bf16x8*)&Kl[tB * 512 + lane * 8];
            f32x4 eB0 = __builtin_amdgcn_mfma_f32_16x16x32_bf16(kfB, qf[0], z, 0, 0, 0);
            f32x4 eB1 = __builtin_amdgcn_mfma_f32_16x16x32_bf16(kfB, qf[1], z, 0, 0, 0);
#pragma unroll
            for (int j = 0; j < 4; ++j) pB[0][j] = exp2_fast(eB0[j]);
#pragma unroll
            for (int j = 0; j < 4; ++j) pB[1][j] = exp2_fast(eB1[j]);
        }
        uint2 ca = *(const uint2*)&cnt[tA * 16 + quad * 4];
        uint2 cc = *(const uint2*)&cnt[tB * 16 + quad * 4];
        bf16x8 cf = bc8((uint4){ca.x, ca.y, cc.x, cc.y});
        uint2 wA0 = *(const uint2*)&Vl[vOffA];
        uint2 wB0 = *(const uint2*)&Vl[vOffB];
        bf16x8 V0 = bc8((uint4){wA0.x, wA0.y, wB0.x, wB0.y});
        uint2 wA1 = *(const uint2*)&Vl[vOffA + 128];
        uint2 wB1 = *(const uint2*)&Vl[vOffB + 128];
        bf16x8 V1 = bc8((uint4){wA1.x, wA1.y, wB1.x, wB1.y});

#pragma unroll
        for (int i = 0; i < 2; ++i) {
            bf16x8 pa = bc8((uint4){cvtpk(pA[i][0], pA[i][1]), cvtpk(pA[i][2], pA[i][3]),
                                    cvtpk(pB[i][0], pB[i][1]), cvtpk(pB[i][2], pB[i][3])});
            o[i][0] = __builtin_amdgcn_mfma_f32_16x16x32_bf16(pa, V0, o[i][0], 0, 0, 0);
            o[i][1] = __builtin_amdgcn_mfma_f32_16x16x32_bf16(pa, V1, o[i][1], 0, 0, 0);
            lv[i]   = __builtin_amdgcn_mfma_f32_16x16x32_bf16(pa, cf, lv[i], 0, 0, 0);
        }
    };

    // prologue: counts (7 x 1KB across waves 0-6, linear) + round 0
    if (w < 7) dma16(crow + w * 512 + lane * 8, (char*)&S[16384] + w * 1024, lane);
    stage(0, 0);

    for (int r = 0; r < 25; ++r) {
        asm volatile("s_waitcnt vmcnt(0)" ::: "memory");   // own stage(r) landed
        __builtin_amdgcn_s_barrier();                      // raw: prefetches stay in flight
        asm volatile("" ::: "memory");
        if (r + 1 < 25) stage(r + 1, (r + 1) & 1);         // flies during body(r)
        round_body(r, r & 1);
    }
    __syncthreads();                           // all waves done; LDS reusable

    // ---- merge 4 roles per q-half (two independent trees) ----
    float* mg = (float*)&S[0];
    {
        int slot = ((qh * 2 + (g & 1)) * 64 + lane) * 24;
        if (g >= 2) {
            *(f32x4*)&mg[slot + 0]  = o[0][0];
            *(f32x4*)&mg[slot + 4]  = o[0][1];
            *(f32x4*)&mg[slot + 8]  = o[1][0];
            *(f32x4*)&mg[slot + 12] = o[1][1];
            *(f32x4*)&mg[slot + 16] = lv[0];
            *(f32x4*)&mg[slot + 20] = lv[1];
        }
        __syncthreads();
        if (g < 2) {
            o[0][0] += *(const f32x4*)&mg[slot + 0];
            o[0][1] += *(const f32x4*)&mg[slot + 4];
            o[1][0] += *(const f32x4*)&mg[slot + 8];
            o[1][1] += *(const f32x4*)&mg[slot + 12];
            lv[0]   += *(const f32x4*)&mg[slot + 16];
            lv[1]   += *(const f32x4*)&mg[slot + 20];
        }
        __syncthreads();
    }
    {
        int slot = (qh * 64 + lane) * 24;
        if (g == 1) {
            *(f32x4*)&mg[slot + 0]  = o[0][0];
            *(f32x4*)&mg[slot + 4]  = o[0][1];
            *(f32x4*)&mg[slot + 8]  = o[1][0];
            *(f32x4*)&mg[slot + 12] = o[1][1];
            *(f32x4*)&mg[slot + 16] = lv[0];
            *(f32x4*)&mg[slot + 20] = lv[1];
        }
        __syncthreads();
        if (g == 0) {
            o[0][0] += *(const f32x4*)&mg[slot + 0];
            o[0][1] += *(const f32x4*)&mg[slot + 4];
            o[1][0] += *(const f32x4*)&mg[slot + 8];
            o[1][1] += *(const f32x4*)&mg[slot + 12];
            lv[0]   += *(const f32x4*)&mg[slot + 16];
            lv[1]   += *(const f32x4*)&mg[slot + 20];
            float gam = gammap[0];
#pragma unroll
            for (int i = 0; i < 2; ++i) {
#pragma unroll
                for (int r2 = 0; r2 < 4; ++r2) {
                    float scl = gam / lv[i][r2];
                    int q = blockIdx.y * 64 + qh * 32 + i * 16 + quad * 4 + r2;
                    size_t base = ((size_t)(b * SQ + q) << 8) + h * 32 + l16;
                    out[base]      = o[i][0][r2] * scl + x[base];
                    out[base + 16] = o[i][1][r2] * scl + x[base + 16];
                }
            }
        }
    }
}

// ---------------- launcher ----------------
extern "C" void kernel_launch(void* const* d_in, const int* in_sizes, int n_in,
                              void* d_out, int out_size, void* d_ws, size_t ws_size,
                              hipStream_t stream) {
    const float* x     = (const float*)d_in[0];
    const float* Wq    = (const float*)d_in[1];
    const float* bq    = (const float*)d_in[2];
    const float* Wk    = (const float*)d_in[3];
    const float* bk    = (const float*)d_in[4];
    const float* Wv    = (const float*)d_in[5];
    const float* bv    = (const float*)d_in[6];
    const float* gamma = (const float*)d_in[7];
    float* out = (float*)d_out;

    u16* ws   = (u16*)d_ws;
    u16* qbf  = ws + WS_Q;
    u16* kbf  = ws + WS_K;
    u16* vbf  = ws + WS_V;
    u16* wtf  = ws + WS_WT;
    u16* crow = ws + WS_CB;
    u16* xbf  = ws + WS_XB;

    xprep_kernel<<<392, 256, 0, stream>>>(x, xbf);
    wprep_kernel<<<dim3(4, 4, 3), 256, 0, stream>>>(Wq, Wk, Wv, wtf, kbf, vbf, crow);
    proj_kernel<<<dim3(98, 3, 2), 256, 0, stream>>>(xbf, wtf, bq, bk, bv, qbf, kbf, vbf);
    attn_kernel<<<dim3(16, 49), 512, 0, stream>>>(qbf, kbf, vbf, crow, x, gamma, out);
}